// Round 4
// baseline (375.319 us; speedup 1.0000x reference)
//
#include <hip/hip_runtime.h>
#include <math.h>

#define CONF 0.25f
#define NCLS 80

// ---------------------------------------------------------------------------
// Kernel 1: score pass. 4 lanes/row, 16 rows per wave, 16 waves per block.
// CHUNK = 16 rows = ONE WAVE: after the in-wave shfl reduce, lane 0 writes
// chunksum/chunkminfail straight to global. No LDS, no __syncthreads, no
// serial per-block tail — round-3's post-mortem: the 16-wave barrier +
// single-thread 16-iter LDS chain serialized every block (~1.5 us x 977
// blocks / 2-deep residency ~= the 20 us gap to the BW floor).
// Loads: all 5 row float4s + box float issued into named regs before use
// (kept from round 3). Boxes read 1 float/lane -> wave reads 256B contig.
// No atomics, no fences (round-1 lesson: per-block device fence = 197 us).
// ---------------------------------------------------------------------------
__global__ __launch_bounds__(1024) void yolo_score(
    const float* __restrict__ logits,
    const float* __restrict__ boxes,
    float* __restrict__ vrow,
    float* __restrict__ chunksum,
    unsigned int* __restrict__ chunkminfail,
    unsigned int k)
{
    const int tid   = threadIdx.x;
    const int lane4 = tid & 3;
    const unsigned int row = blockIdx.x * 256u + (unsigned int)(tid >> 2);

    float v = 0.0f;                                     // lane0-of-group only
    unsigned int failrow = 0xFFFFFFFFu;

    if (row < k) {
        const float4* rp = (const float4*)(logits + (size_t)row * NCLS);
        // issue all 6 loads back-to-back
        float4 c0 = rp[lane4 +  0];
        float4 c1 = rp[lane4 +  4];
        float4 c2 = rp[lane4 +  8];
        float4 c3 = rp[lane4 + 12];
        float4 c4 = rp[lane4 + 16];
        float  bx = boxes[4u * row + (unsigned int)lane4];

        float m0 = fmaxf(fmaxf(c0.x, c0.y), fmaxf(c0.z, c0.w));
        float m1 = fmaxf(fmaxf(c1.x, c1.y), fmaxf(c1.z, c1.w));
        float m2 = fmaxf(fmaxf(c2.x, c2.y), fmaxf(c2.z, c2.w));
        float m3 = fmaxf(fmaxf(c3.x, c3.y), fmaxf(c3.z, c3.w));
        float m4 = fmaxf(fmaxf(c4.x, c4.y), fmaxf(c4.z, c4.w));
        float m  = fmaxf(fmaxf(fmaxf(m0, m1), fmaxf(m2, m3)), m4);

        // aligned 4-lane group: max(m), sum(bx)
        m  = fmaxf(m, __shfl_xor(m, 1));
        m  = fmaxf(m, __shfl_xor(m, 2));
        bx += __shfl_xor(bx, 1);
        bx += __shfl_xor(bx, 2);

        if (lane4 == 0) {
            v = m + bx;
            vrow[row] = v;
            if (m < CONF) failrow = row;                // essentially-never
        }
    }

    // in-wave reduce: sum of v (non-lane0 hold 0), min of failrow
    float sv = v;
    unsigned int wf = failrow;
#pragma unroll
    for (int o = 32; o > 0; o >>= 1) {
        sv += __shfl_down(sv, o);
        wf = min(wf, __shfl_down(wf, o));
    }

    // per-WAVE chunk write: chunk c = global wave id covers rows [16c,16c+16)
    if ((tid & 63) == 0) {
        const unsigned int c = blockIdx.x * 16u + (unsigned int)(tid >> 6);
        if (c * 16u < k) {                              // chunk has valid rows
            chunksum[c]     = sv;
            chunkminfail[c] = wf;
        }
    }
}

// ---------------------------------------------------------------------------
// Kernel 2: single-block finish, 1024 threads. ncw = ceil(k/16) = 15625
// chunks -> ~16 strided elements/thread, fully parallel, ~125 KB read.
// j = min(chunkminfail) clamped to k; out = full 16-row chunks below j +
// boundary rows from vrow. Fixed per-thread stride order -> deterministic.
// ---------------------------------------------------------------------------
__global__ __launch_bounds__(1024) void yolo_finish(
    const float* __restrict__ vrow,
    const float* __restrict__ chunksum,
    const unsigned int* __restrict__ chunkminfail,
    float* __restrict__ out,
    unsigned int k, unsigned int ncw)
{
    const int tid  = threadIdx.x;
    const int lane = tid & 63;
    const int wid  = tid >> 6;

    __shared__ unsigned int lsj[16];
    __shared__ float        lsv[16];
    __shared__ unsigned int jsh;

    // 1) global first failing row
    unsigned int jmin = 0xFFFFFFFFu;
    for (unsigned int c = (unsigned int)tid; c < ncw; c += 1024u)
        jmin = min(jmin, chunkminfail[c]);
#pragma unroll
    for (int o = 32; o > 0; o >>= 1) jmin = min(jmin, __shfl_down(jmin, o));
    if (lane == 0) lsj[wid] = jmin;
    __syncthreads();
    if (tid == 0) {
        unsigned int j = 0xFFFFFFFFu;
#pragma unroll
        for (int w = 0; w < 16; ++w) j = min(j, lsj[w]);
        jsh = (j > k) ? k : j;
    }
    __syncthreads();
    const unsigned int j = jsh;

    // 2) sum full 16-row chunks below j, plus boundary rows [cfull*16, j)
    const unsigned int cfull = j >> 4;
    float s = 0.0f;
    for (unsigned int c = (unsigned int)tid; c < cfull; c += 1024u)
        s += chunksum[c];
    const unsigned int nbd = j & 15u;
    if ((unsigned int)tid < nbd)
        s += vrow[(size_t)cfull * 16u + (unsigned int)tid];

#pragma unroll
    for (int o = 32; o > 0; o >>= 1) s += __shfl_down(s, o);
    if (lane == 0) lsv[wid] = s;
    __syncthreads();
    if (tid == 0) {
        float t = 0.0f;
#pragma unroll
        for (int w = 0; w < 16; ++w) t += lsv[w];
        out[0] = t;
    }
}

extern "C" void kernel_launch(void* const* d_in, const int* in_sizes, int n_in,
                              void* d_out, int out_size, void* d_ws, size_t ws_size,
                              hipStream_t stream) {
    const float* logits = (const float*)d_in[0];
    const float* boxes  = (const float*)d_in[1];
    float* out = (float*)d_out;

    const unsigned int N = (unsigned int)(in_sizes[0] / NCLS);
    unsigned int k = N / 4;                              // RATIO = 0.25
    if (k < 1) k = 1;
    const unsigned int nb  = (k + 255u) / 256u;          // 256 rows per block
    const unsigned int ncw = (k + 15u) / 16u;            // 16 rows per chunk/wave

    // ws layout (256B-aligned sections):
    //   [0]   chunkminfail (ncw u32)
    //   [..]  chunksum     (ncw f32)
    //   [..]  vrow         (k   f32)
    char* ws = (char*)d_ws;
    size_t off = 0;
    unsigned int* cmf = (unsigned int*)(ws + off);
    off += ((size_t)ncw * 4 + 255) & ~(size_t)255;
    float* csum = (float*)(ws + off);
    off += ((size_t)ncw * 4 + 255) & ~(size_t)255;
    float* vrow = (float*)(ws + off);

    yolo_score<<<nb, 1024, 0, stream>>>(logits, boxes, vrow, csum, cmf, k);
    yolo_finish<<<1, 1024, 0, stream>>>(vrow, csum, cmf, out, k, ncw);
}